// Round 1
// baseline (257.011 us; speedup 1.0000x reference)
//
#include <hip/hip_runtime.h>

// ---------------------------------------------------------------------------
// SpectralMamba fused kernel (MI355X / gfx950)
//
// rows n = (b,h,w), u[n][c] = x[b][c][h][w];  out[b][c][h][w] = y1[n][c]
// Pipeline per 64-row tile (one workgroup, 8 waves):
//   GEMM1 xz = u @ W_in            (K=256, N=1024)  -> xc=silu(xi*cw+cb), sz=silu(z)
//   GEMM2 dbc = xc @ W_xproj       (K=512, N=48)    -> dt, Bm, Cm, bc=sum(Bm*Cm)
//   GEMM3 delta = softplus(dt@W_dt + b_dt)  (K=16 padded to 32, N=512)
//   y = (delta*bc + D) * xc * sz
//   GEMM4 out = y @ W_out          (K=512, N=256)
// All matmuls: v_mfma_f32_16x16x32_f16, fp32 accum. Weights pre-packed to f16
// B-fragment layout [k/8][n][k%8] in d_ws by pack_w_kernel.
// ---------------------------------------------------------------------------

typedef _Float16 f16x8 __attribute__((ext_vector_type(8)));
typedef float f32x4 __attribute__((ext_vector_type(4)));

#define MFMA16(a,b,c) __builtin_amdgcn_mfma_f32_16x16x32_f16((a),(b),(c),0,0,0)

// workspace layout (bytes)
#define WPIN_OFF   0u        // 32kb x 1024 x 8 f16 = 512 KB
#define WPOUT_OFF  524288u   // 64kb x 256 x 8      = 256 KB
#define WPXP_OFF   786432u   // 64kb x 48  x 8      = 48 KB
#define WPDT_OFF   835584u   // 4kb  x 512 x 8      = 32 KB (kb>=2 zero pad)

// LDS layout (bytes)
#define U_OFF     0          // u pack:  [32 kb][64 m][8 ke] f16 = 32 KB
#define XC_OFF    32768      // xc/y pack: [64 kb][64 m][8 ke] f16 = 64 KB
#define DBC_OFF   98304      // dbc: [64 m][49 stride] f32 = 12544 B
#define DBC_STR   49
#define DTP_OFF   110848     // dt pack: [4 kb][64 m][8 ke] f16 = 4 KB
#define BC_OFF    114944     // bc: [64] f32
#define LDS_BYTES 115200

__device__ __forceinline__ unsigned short f16bits(float f) {
  union { _Float16 h; unsigned short u; } c; c.h = (_Float16)f; return c.u;
}
__device__ __forceinline__ float f16val(unsigned short b) {
  union { unsigned short u; _Float16 h; } c; c.u = b; return (float)c.h;
}

// pack fp32 [K][N] weight -> f16 fragment layout [KB][N][8], zero-pad k>=K
__global__ void pack_w_kernel(const float* __restrict__ src,
                              unsigned short* __restrict__ dst,
                              int K, int N, int KB) {
  int t = blockIdx.x * 256 + threadIdx.x;
  if (t >= KB * N * 8) return;
  int ke = t & 7;
  int n  = (t >> 3) % N;
  int kb = t / (N * 8);
  int k  = kb * 8 + ke;
  float v = (k < K) ? src[k * N + n] : 0.f;
  dst[t] = f16bits(v);
}

__global__ __launch_bounds__(512) void mamba_fused_kernel(
    const float* __restrict__ x,
    const float* __restrict__ conv_w,
    const float* __restrict__ conv_b,
    const float* __restrict__ b_dt,
    const float* __restrict__ Dvec,
    float* __restrict__ out,
    const char* __restrict__ ws)
{
  __shared__ __align__(16) char smem[LDS_BYTES];

  const int tid  = threadIdx.x;
  const int wv   = tid >> 6;     // wave 0..7
  const int l    = tid & 63;
  const int lrow = l & 15;       // tile col (C) / tile row (A)
  const int lhi  = l >> 4;       // k-group / row-group

  const int wg   = blockIdx.x;
  const int w0   = (wg & 1) << 6;
  const int hb   = wg >> 1;
  const int h    = hb & 127;
  const int bidx = hb >> 7;

  // zero dt-pack kb=2,3 (K padding for GEMM3)
  if (tid < 128) {
    f32x4 z4 = {0.f, 0.f, 0.f, 0.f};
    *(f32x4*)(smem + DTP_OFF + 2048 + tid * 16) = z4;
  }

  // ---------------- phase 1: load u tile -> LDS A-pack ----------------
  {
    const float* xb = x + ((long)(bidx * 256) * 128 + h) * 128 + w0;
    #pragma unroll
    for (int i = 0; i < 4; ++i) {
      int cg = i * 8 + wv;             // channel group 0..31 (8 channels each)
      unsigned short us[8];
      #pragma unroll
      for (int j = 0; j < 8; ++j) {
        float f = __builtin_nontemporal_load(xb + (long)(cg * 8 + j) * 16384 + l);
        us[j] = f16bits(f);
      }
      uint4 pk;
      pk.x = us[0] | ((unsigned)us[1] << 16);
      pk.y = us[2] | ((unsigned)us[3] << 16);
      pk.z = us[4] | ((unsigned)us[5] << 16);
      pk.w = us[6] | ((unsigned)us[7] << 16);
      *(uint4*)(smem + U_OFF + (cg * 64 + l) * 16) = pk;
    }
  }
  __syncthreads();

  unsigned int xc_p[4][8];   // xc, f16x2 packed: [q][rt*2 + i/2]
  unsigned int sz_p[4][8];   // silu(z)

  // ---------------- phase 2: GEMM1 xz = u @ W_in ----------------
  {
    const f16x8* wp_in = (const f16x8*)(ws + WPIN_OFF);
    #pragma unroll
    for (int hf = 0; hf < 2; ++hf) {           // 0: xi cols, 1: z cols
      f32x4 acc[4][4];
      #pragma unroll
      for (int q = 0; q < 4; ++q)
        #pragma unroll
        for (int rt = 0; rt < 4; ++rt) {
          f32x4 z4 = {0.f, 0.f, 0.f, 0.f};
          acc[q][rt] = z4;
        }
      const int cb = hf * 512 + wv * 64;
      #pragma unroll
      for (int s = 0; s < 8; ++s) {
        f16x8 a[4];
        #pragma unroll
        for (int rt = 0; rt < 4; ++rt)
          a[rt] = *(const f16x8*)(smem + U_OFF + ((s * 4 + lhi) * 64 + rt * 16 + lrow) * 16);
        f16x8 bq[4];
        #pragma unroll
        for (int q = 0; q < 4; ++q)
          bq[q] = wp_in[(s * 4 + lhi) * 1024 + cb + q * 16 + lrow];
        #pragma unroll
        for (int q = 0; q < 4; ++q)
          #pragma unroll
          for (int rt = 0; rt < 4; ++rt)
            acc[q][rt] = MFMA16(a[rt], bq[q], acc[q][rt]);
      }
      // epilogue
      #pragma unroll
      for (int q = 0; q < 4; ++q) {
        const int j = wv * 64 + q * 16 + lrow;   // inner column 0..511
        if (hf == 0) {
          const float cw  = conv_w[j * 4 + 3];
          const float cbv = conv_b[j];
          #pragma unroll
          for (int rt = 0; rt < 4; ++rt) {
            unsigned int lo = 0;
            #pragma unroll
            for (int i = 0; i < 4; ++i) {
              float t  = acc[q][rt][i] * cw + cbv;
              float sv = t / (1.f + __expf(-t));            // silu
              unsigned short bb16 = f16bits(sv);
              if ((i & 1) == 0) lo = bb16;
              else xc_p[q][rt * 2 + (i >> 1)] = lo | ((unsigned)bb16 << 16);
              int m = rt * 16 + lhi * 4 + i;
              *(unsigned short*)(smem + XC_OFF + ((j >> 3) * 64 + m) * 16 + (j & 7) * 2) = bb16;
            }
          }
        } else {
          #pragma unroll
          for (int rt = 0; rt < 4; ++rt) {
            unsigned int lo = 0;
            #pragma unroll
            for (int i = 0; i < 4; ++i) {
              float t  = acc[q][rt][i];
              float sv = t / (1.f + __expf(-t));            // silu(z)
              unsigned short bb16 = f16bits(sv);
              if ((i & 1) == 0) lo = bb16;
              else sz_p[q][rt * 2 + (i >> 1)] = lo | ((unsigned)bb16 << 16);
            }
          }
        }
      }
    }
  }
  __syncthreads();

  // ---------------- phase 3: GEMM2 dbc = xc @ W_xproj ----------------
  {
    const f16x8* wp_xp = (const f16x8*)(ws + WPXP_OFF);
    const int rt2 = wv & 3;
    f32x4 acc2[2];
    { f32x4 z4 = {0.f,0.f,0.f,0.f}; acc2[0] = z4; acc2[1] = z4; }
    #pragma unroll
    for (int s = 0; s < 16; ++s) {
      f16x8 a = *(const f16x8*)(smem + XC_OFF + ((s * 4 + lhi) * 64 + rt2 * 16 + lrow) * 16);
      if (wv < 4) {
        f16x8 b0 = wp_xp[(s * 4 + lhi) * 48 + lrow];        // ct=0 (dt)
        f16x8 b2 = wp_xp[(s * 4 + lhi) * 48 + 32 + lrow];   // ct=2 (Cm)
        acc2[0] = MFMA16(a, b0, acc2[0]);
        acc2[1] = MFMA16(a, b2, acc2[1]);
      } else {
        f16x8 b1 = wp_xp[(s * 4 + lhi) * 48 + 16 + lrow];   // ct=1 (Bm)
        acc2[0] = MFMA16(a, b1, acc2[0]);
      }
    }
    if (wv < 4) {
      #pragma unroll
      for (int i = 0; i < 4; ++i) {
        int m = rt2 * 16 + lhi * 4 + i;
        *(float*)(smem + DBC_OFF + (m * DBC_STR + lrow) * 4)      = acc2[0][i];
        *(float*)(smem + DBC_OFF + (m * DBC_STR + 32 + lrow) * 4) = acc2[1][i];
        // dt pack for GEMM3 A-operand (cols 0..15 -> kb 0,1)
        *(unsigned short*)(smem + DTP_OFF + ((lrow >> 3) * 64 + m) * 16 + (lrow & 7) * 2)
            = f16bits(acc2[0][i]);
      }
    } else {
      #pragma unroll
      for (int i = 0; i < 4; ++i) {
        int m = rt2 * 16 + lhi * 4 + i;
        *(float*)(smem + DBC_OFF + (m * DBC_STR + 16 + lrow) * 4) = acc2[0][i];
      }
    }
  }
  __syncthreads();

  // ---------------- phase 3.5: bc[m] = sum(Bm*Cm) ----------------
  if (tid < 64) {
    const float* dbcp = (const float*)(smem + DBC_OFF) + tid * DBC_STR;
    float s = 0.f;
    #pragma unroll
    for (int j = 0; j < 16; ++j) s += dbcp[16 + j] * dbcp[32 + j];
    *(float*)(smem + BC_OFF + tid * 4) = s;
  }
  __syncthreads();

  // ---------------- phase 4: GEMM3 delta + recombine y ----------------
  {
    const f16x8* wp_dt = (const f16x8*)(ws + WPDT_OFF);
    f16x8 a3[4];
    #pragma unroll
    for (int rt = 0; rt < 4; ++rt)
      a3[rt] = *(const f16x8*)(smem + DTP_OFF + (lhi * 64 + rt * 16 + lrow) * 16);
    #pragma unroll
    for (int q = 0; q < 4; ++q) {
      const int col  = wv * 64 + q * 16 + lrow;
      const float bias = b_dt[col];
      const float dcol = Dvec[col];
      f16x8 b3 = wp_dt[lhi * 512 + col];
      f32x4 cin = {bias, bias, bias, bias};
      f32x4 acc3[4];
      #pragma unroll
      for (int rt = 0; rt < 4; ++rt)
        acc3[rt] = MFMA16(a3[rt], b3, cin);
      #pragma unroll
      for (int rt = 0; rt < 4; ++rt) {
        #pragma unroll
        for (int i = 0; i < 4; ++i) {
          int m = rt * 16 + lhi * 4 + i;
          float t = acc3[rt][i];
          float delta = (t > 20.f) ? t : __logf(1.f + __expf(t));  // softplus
          float bcm = *(const float*)(smem + BC_OFF + m * 4);      // broadcast read
          unsigned int xb = xc_p[q][rt * 2 + (i >> 1)];
          unsigned int zb = sz_p[q][rt * 2 + (i >> 1)];
          float xc = f16val((i & 1) ? (unsigned short)(xb >> 16) : (unsigned short)(xb & 0xffffu));
          float sz = f16val((i & 1) ? (unsigned short)(zb >> 16) : (unsigned short)(zb & 0xffffu));
          float y = (delta * bcm + dcol) * xc * sz;
          *(unsigned short*)(smem + XC_OFF + ((col >> 3) * 64 + m) * 16 + (col & 7) * 2) = f16bits(y);
        }
      }
    }
  }
  __syncthreads();

  // ---------------- phase 5: GEMM4 out = y @ W_out ----------------
  {
    const f16x8* wp_out = (const f16x8*)(ws + WPOUT_OFF);
    f32x4 acc4[2][4];
    #pragma unroll
    for (int c2 = 0; c2 < 2; ++c2)
      #pragma unroll
      for (int rt = 0; rt < 4; ++rt) {
        f32x4 z4 = {0.f, 0.f, 0.f, 0.f};
        acc4[c2][rt] = z4;
      }
    #pragma unroll
    for (int s = 0; s < 16; ++s) {
      f16x8 a[4];
      #pragma unroll
      for (int rt = 0; rt < 4; ++rt)
        a[rt] = *(const f16x8*)(smem + XC_OFF + ((s * 4 + lhi) * 64 + rt * 16 + lrow) * 16);
      f16x8 bw[2];
      #pragma unroll
      for (int c2 = 0; c2 < 2; ++c2)
        bw[c2] = wp_out[(s * 4 + lhi) * 256 + wv * 32 + c2 * 16 + lrow];
      #pragma unroll
      for (int c2 = 0; c2 < 2; ++c2)
        #pragma unroll
        for (int rt = 0; rt < 4; ++rt)
          acc4[c2][rt] = MFMA16(a[rt], bw[c2], acc4[c2][rt]);
    }
    #pragma unroll
    for (int c2 = 0; c2 < 2; ++c2) {
      const int c = wv * 32 + c2 * 16 + lrow;
      float* ob = out + (((long)(bidx * 256 + c)) * 128 + h) * 128 + w0;
      #pragma unroll
      for (int rt = 0; rt < 4; ++rt)
        #pragma unroll
        for (int i = 0; i < 4; ++i) {
          int m = rt * 16 + lhi * 4 + i;
          __builtin_nontemporal_store(acc4[c2][rt][i], ob + m);
        }
    }
  }
}

extern "C" void kernel_launch(void* const* d_in, const int* in_sizes, int n_in,
                              void* d_out, int out_size, void* d_ws, size_t ws_size,
                              hipStream_t stream) {
  const float* x       = (const float*)d_in[0];
  const float* W_in    = (const float*)d_in[1];
  const float* conv_w  = (const float*)d_in[2];
  const float* conv_b  = (const float*)d_in[3];
  const float* W_xproj = (const float*)d_in[4];
  const float* W_dt    = (const float*)d_in[5];
  const float* b_dt    = (const float*)d_in[6];
  // d_in[7] = A_log: unused by the reference's L=1 path
  const float* Dvec    = (const float*)d_in[8];
  const float* W_out   = (const float*)d_in[9];
  float* out = (float*)d_out;
  char* ws = (char*)d_ws;

  // pack weights to f16 MFMA B-fragment layout (once per launch, ~870 KB)
  pack_w_kernel<<<dim3(1024), dim3(256), 0, stream>>>(W_in,    (unsigned short*)(ws + WPIN_OFF), 256, 1024, 32);
  pack_w_kernel<<<dim3(512),  dim3(256), 0, stream>>>(W_out,   (unsigned short*)(ws + WPOUT_OFF), 512, 256, 64);
  pack_w_kernel<<<dim3(96),   dim3(256), 0, stream>>>(W_xproj, (unsigned short*)(ws + WPXP_OFF), 512, 48, 64);
  pack_w_kernel<<<dim3(64),   dim3(256), 0, stream>>>(W_dt,    (unsigned short*)(ws + WPDT_OFF), 16, 512, 4);

  // 2048 workgroups x 512 threads; each handles 64 rows (one half w-line)
  mamba_fused_kernel<<<dim3(2048), dim3(512), 0, stream>>>(
      x, conv_w, conv_b, b_dt, Dvec, out, (const char*)ws);
}

// Round 3
// 194.424 us; speedup vs baseline: 1.3219x; 1.3219x over previous
//
#include <hip/hip_runtime.h>

// ---------------------------------------------------------------------------
// SpectralMamba fused kernel (MI355X / gfx950) — R2: swapped-operand MFMAs
//
// All GEMMs computed as D[outcol][m] = W^T @ act (weights = A operand):
//  - lane holds 4 CONSECUTIVE outcols at fixed row m -> vectorized b64 LDS
//    writes of f16 pairs (cvt_pkrtz), vs 64 scalar b16 writes before.
//  - conv_w folded into f16 W_in pack; conv_b / b_dt applied as MFMA C-in.
//  - bc = sum(Bm*Cm) reduced in-register (shfl_xor), no DBC LDS buffer.
//  - LDS 115 KB -> 68.3 KB (U tile union'd with XC) -> 2 blocks/CU.
// ---------------------------------------------------------------------------

typedef _Float16 f16x8 __attribute__((ext_vector_type(8)));
typedef _Float16 f16x2 __attribute__((ext_vector_type(2)));
typedef __fp16 fp16x2b __attribute__((ext_vector_type(2)));   // builtin return type
typedef float f32x4 __attribute__((ext_vector_type(4)));

#define MFMA16(a,b,c) __builtin_amdgcn_mfma_f32_16x16x32_f16((a),(b),(c),0,0,0)

// workspace layout (bytes): packs are [k/8][outcol][k%8] f16 = W[k][outcol]
#define WPIN_OFF   0u        // 32kb x 1024 x 8 f16 = 512 KB (xi half pre-scaled by conv_w[:,3])
#define WPOUT_OFF  524288u   // 64kb x 256  x 8     = 256 KB
#define WPXP_OFF   786432u   // 64kb x 48   x 8     = 48 KB
#define WPDT_OFF   835584u   // 4kb  x 512  x 8     = 32 KB (kb>=2 zero pad)

// LDS layout (bytes). U region (phase 1-2) is union'd with XC (phase >=3).
#define U_OFF     0          // u pack:  [32 k8][64 m][8] f16 = 32 KB
#define XC_OFF    0          // xc/y pack: [64 k8][64 m][8] f16 = 64 KB
#define DTP_OFF   65536      // dt pack: [4 k8][64 m][8] f16 = 4 KB (k8>=2 zeros)
#define BC_OFF    69632      // bc: [64] f32
#define LDS_BYTES 69888

__device__ __forceinline__ unsigned short f16bits(float f) {
  union { _Float16 h; unsigned short u; } c; c.h = (_Float16)f; return c.u;
}
__device__ __forceinline__ unsigned pk2(float a, float b) {
  union { fp16x2b h; unsigned u; } c;
  c.h = __builtin_amdgcn_cvt_pkrtz(a, b);
  return c.u;
}
__device__ __forceinline__ f16x2 upk(unsigned u) {
  union { unsigned u; f16x2 h; } c; c.u = u; return c.h;
}
__device__ __forceinline__ float siluf(float t) {
  return t * __builtin_amdgcn_rcpf(1.f + __expf(-t));
}
__device__ __forceinline__ float softplusf(float t) {
  return fmaxf(t, 0.f) + __logf(1.f + __expf(-fabsf(t)));
}

// pack fp32 [K][N] weight -> f16 fragment layout [KB][N][8], zero-pad k>=K
__global__ void pack_w_kernel(const float* __restrict__ src,
                              unsigned short* __restrict__ dst,
                              int K, int N, int KB) {
  int t = blockIdx.x * 256 + threadIdx.x;
  if (t >= KB * N * 8) return;
  int ke = t & 7;
  int n  = (t >> 3) % N;
  int kb = t / (N * 8);
  int k  = kb * 8 + ke;
  float v = (k < K) ? src[k * N + n] : 0.f;
  dst[t] = f16bits(v);
}

// pack W_in with conv_w[:,3] folded into the xi half (cols 0..511)
__global__ void pack_win_kernel(const float* __restrict__ W_in,
                                const float* __restrict__ conv_w,
                                unsigned short* __restrict__ dst) {
  int t = blockIdx.x * 256 + threadIdx.x;   // 32*1024*8 = 262144 total
  int ke = t & 7;
  int n  = (t >> 3) & 1023;
  int kb = t >> 13;
  float v = W_in[(kb * 8 + ke) * 1024 + n];
  if (n < 512) v *= conv_w[n * 4 + 3];
  dst[t] = f16bits(v);
}

__global__ __launch_bounds__(512, 4) void mamba_fused_kernel(
    const float* __restrict__ x,
    const float* __restrict__ conv_b,
    const float* __restrict__ b_dt,
    const float* __restrict__ Dvec,
    float* __restrict__ out,
    const char* __restrict__ ws)
{
  __shared__ __align__(16) char smem[LDS_BYTES];

  const int tid  = threadIdx.x;
  const int wv   = tid >> 6;     // wave 0..7
  const int l    = tid & 63;
  const int lrow = l & 15;       // C col (= row m) / A row (= outcol)
  const int lhi  = l >> 4;       // k-group / outcol sub-group

  const int wg   = blockIdx.x;
  const int w0   = (wg & 1) << 6;
  const int hb   = wg >> 1;
  const int h    = hb & 127;
  const int bidx = hb >> 7;

  // zero dt-pack k8=2,3 (K padding for GEMM3)
  if (tid < 128) {
    f32x4 z4 = {0.f, 0.f, 0.f, 0.f};
    *(f32x4*)(smem + DTP_OFF + 2048 + tid * 16) = z4;
  }

  // ---------------- phase 1: load u tile -> LDS B-pack [c/8][m][c%8] -------
  {
    const float* xb = x + ((long)(bidx * 256) * 128 + h) * 128 + w0;
    #pragma unroll
    for (int i = 0; i < 4; ++i) {
      int cg = i * 8 + wv;             // channel group 0..31 (8 channels each)
      float f[8];
      #pragma unroll
      for (int j = 0; j < 8; ++j)
        f[j] = __builtin_nontemporal_load(xb + (long)(cg * 8 + j) * 16384 + l);
      uint4 pk;
      pk.x = pk2(f[0], f[1]); pk.y = pk2(f[2], f[3]);
      pk.z = pk2(f[4], f[5]); pk.w = pk2(f[6], f[7]);
      *(uint4*)(smem + U_OFF + (cg * 64 + l) * 16) = pk;
    }
  }
  __syncthreads();

  unsigned xc_p[4][4][2];   // xc f16 pairs: [q][rt][pair]; j = wv*64+q*16+lhi*4+{2p,2p+1}, m = rt*16+lrow
  unsigned sz_p[4][4][2];   // silu(z), same layout

  // ---------------- phase 2: GEMM1 xz^T = W_in^T @ u^T ----------------
  {
    const f16x8* wp_in = (const f16x8*)(ws + WPIN_OFF);
    #pragma unroll
    for (int hf = 0; hf < 2; ++hf) {           // 0: xi cols (conv folded), 1: z cols
      const int cb = hf * 512 + wv * 64;
      #pragma unroll
      for (int qh = 0; qh < 2; ++qh) {         // split q to cap VGPR peak
        f32x4 acc[2][4];
        #pragma unroll
        for (int q2 = 0; q2 < 2; ++q2) {
          if (hf == 0) {
            f32x4 cb4 = *(const f32x4*)(conv_b + cb + (qh * 2 + q2) * 16 + lhi * 4);
            #pragma unroll
            for (int rt = 0; rt < 4; ++rt) acc[q2][rt] = cb4;
          } else {
            f32x4 z4 = {0.f, 0.f, 0.f, 0.f};
            #pragma unroll
            for (int rt = 0; rt < 4; ++rt) acc[q2][rt] = z4;
          }
        }
        __builtin_amdgcn_s_setprio(1);
        #pragma unroll
        for (int s = 0; s < 8; ++s) {
          f16x8 b[4];
          #pragma unroll
          for (int rt = 0; rt < 4; ++rt)
            b[rt] = *(const f16x8*)(smem + U_OFF + ((s * 4 + lhi) * 64 + rt * 16 + lrow) * 16);
          f16x8 a[2];
          #pragma unroll
          for (int q2 = 0; q2 < 2; ++q2)
            a[q2] = wp_in[(s * 4 + lhi) * 1024 + cb + (qh * 2 + q2) * 16 + lrow];
          #pragma unroll
          for (int q2 = 0; q2 < 2; ++q2)
            #pragma unroll
            for (int rt = 0; rt < 4; ++rt)
              acc[q2][rt] = MFMA16(a[q2], b[rt], acc[q2][rt]);
        }
        __builtin_amdgcn_s_setprio(0);
        #pragma unroll
        for (int q2 = 0; q2 < 2; ++q2) {
          const int q = qh * 2 + q2;
          #pragma unroll
          for (int rt = 0; rt < 4; ++rt) {
            float s0 = siluf(acc[q2][rt][0]);
            float s1 = siluf(acc[q2][rt][1]);
            float s2 = siluf(acc[q2][rt][2]);
            float s3 = siluf(acc[q2][rt][3]);
            if (hf == 0) {
              xc_p[q][rt][0] = pk2(s0, s1); xc_p[q][rt][1] = pk2(s2, s3);
            } else {
              sz_p[q][rt][0] = pk2(s0, s1); sz_p[q][rt][1] = pk2(s2, s3);
            }
          }
        }
      }
    }
  }
  __syncthreads();   // U dead; XC region may now be written

  // ---------------- phase 2.5: xc -> LDS pack [j/8][m][j%8] ----------------
  {
    #pragma unroll
    for (int q = 0; q < 4; ++q) {
      const int j0 = wv * 64 + q * 16 + lhi * 4;
      char* base = smem + XC_OFF + ((j0 >> 3) * 64) * 16 + (j0 & 7) * 2;
      #pragma unroll
      for (int rt = 0; rt < 4; ++rt) {
        uint2 w2; w2.x = xc_p[q][rt][0]; w2.y = xc_p[q][rt][1];
        *(uint2*)(base + (rt * 16 + lrow) * 16) = w2;
      }
    }
  }
  __syncthreads();

  // ---------------- phase 3: GEMM2 dbc^T = W_xproj^T @ xc^T ----------------
  // waves 0-3: Bm & Cm tiles (mt=wv) + in-register bc reduce
  // waves 4-7: dt tile (mt=wv-4) -> DTP pack
  {
    const f16x8* wp_xp = (const f16x8*)(ws + WPXP_OFF);
    if (wv < 4) {
      const int mt = wv;
      f32x4 accB = {0.f,0.f,0.f,0.f}, accC = {0.f,0.f,0.f,0.f};
      #pragma unroll
      for (int s = 0; s < 16; ++s) {
        f16x8 bx = *(const f16x8*)(smem + XC_OFF + ((s * 4 + lhi) * 64 + mt * 16 + lrow) * 16);
        f16x8 aB = wp_xp[(s * 4 + lhi) * 48 + 16 + lrow];
        f16x8 aC = wp_xp[(s * 4 + lhi) * 48 + 32 + lrow];
        accB = MFMA16(aB, bx, accB);
        accC = MFMA16(aC, bx, accC);
      }
      float sbc = accB[0]*accC[0] + accB[1]*accC[1] + accB[2]*accC[2] + accB[3]*accC[3];
      sbc += __shfl_xor(sbc, 16);
      sbc += __shfl_xor(sbc, 32);
      if (lhi == 0)
        *(float*)(smem + BC_OFF + (mt * 16 + lrow) * 4) = sbc;
    } else {
      const int mt = wv - 4;
      f32x4 accD = {0.f,0.f,0.f,0.f};
      #pragma unroll
      for (int s = 0; s < 16; ++s) {
        f16x8 bx = *(const f16x8*)(smem + XC_OFF + ((s * 4 + lhi) * 64 + mt * 16 + lrow) * 16);
        f16x8 aD = wp_xp[(s * 4 + lhi) * 48 + lrow];
        accD = MFMA16(aD, bx, accD);
      }
      const int p0 = lhi * 4;
      uint2 w2; w2.x = pk2(accD[0], accD[1]); w2.y = pk2(accD[2], accD[3]);
      *(uint2*)(smem + DTP_OFF + ((p0 >> 3) * 64 + mt * 16 + lrow) * 16 + (p0 & 7) * 2) = w2;
    }
  }
  __syncthreads();

  // ---------------- phase 4: GEMM3 delta^T = W_dt^T @ dt^T + recombine y ---
  {
    const f16x8* wp_dt = (const f16x8*)(ws + WPDT_OFF);
    const int cb0 = wv * 64;
    f16x8 b3[4];
    #pragma unroll
    for (int rt = 0; rt < 4; ++rt)
      b3[rt] = *(const f16x8*)(smem + DTP_OFF + (lhi * 64 + rt * 16 + lrow) * 16);
    float bcr[4];
    #pragma unroll
    for (int rt = 0; rt < 4; ++rt)
      bcr[rt] = *(const float*)(smem + BC_OFF + (rt * 16 + lrow) * 4);
    #pragma unroll
    for (int q = 0; q < 4; ++q) {
      const int j0 = cb0 + q * 16 + lhi * 4;
      f32x4 bd = *(const f32x4*)(b_dt + j0);
      f32x4 dv = *(const f32x4*)(Dvec + j0);
      f16x8 a3 = wp_dt[lhi * 512 + cb0 + q * 16 + lrow];
      f32x4 acc3[4];
      #pragma unroll
      for (int rt = 0; rt < 4; ++rt)
        acc3[rt] = MFMA16(a3, b3[rt], bd);
      char* xbase = smem + XC_OFF + ((j0 >> 3) * 64) * 16 + (j0 & 7) * 2;
      #pragma unroll
      for (int rt = 0; rt < 4; ++rt) {
        uint2 yw;
        #pragma unroll
        for (int p = 0; p < 2; ++p) {
          f16x2 xv = upk(xc_p[q][rt][p]);
          f16x2 zv = upk(sz_p[q][rt][p]);
          f16x2 pr = xv * zv;                       // v_pk_mul_f16
          float d0 = softplusf(acc3[rt][2 * p]);
          float d1 = softplusf(acc3[rt][2 * p + 1]);
          float y0 = (d0 * bcr[rt] + dv[2 * p])     * (float)pr[0];
          float y1 = (d1 * bcr[rt] + dv[2 * p + 1]) * (float)pr[1];
          unsigned u = pk2(y0, y1);
          if (p == 0) yw.x = u; else yw.y = u;
        }
        *(uint2*)(xbase + (rt * 16 + lrow) * 16) = yw;
      }
    }
  }
  __syncthreads();

  // ---------------- phase 5: GEMM4 out^T = W_out^T @ y^T ----------------
  {
    const f16x8* wp_out = (const f16x8*)(ws + WPOUT_OFF);
    f32x4 acc4[2][4];
    #pragma unroll
    for (int c2 = 0; c2 < 2; ++c2)
      #pragma unroll
      for (int mt = 0; mt < 4; ++mt) {
        f32x4 z4 = {0.f, 0.f, 0.f, 0.f};
        acc4[c2][mt] = z4;
      }
    __builtin_amdgcn_s_setprio(1);
    #pragma unroll
    for (int s = 0; s < 16; ++s) {
      f16x8 by[4];
      #pragma unroll
      for (int mt = 0; mt < 4; ++mt)
        by[mt] = *(const f16x8*)(smem + XC_OFF + ((s * 4 + lhi) * 64 + mt * 16 + lrow) * 16);
      f16x8 aw[2];
      #pragma unroll
      for (int c2 = 0; c2 < 2; ++c2)
        aw[c2] = wp_out[(s * 4 + lhi) * 256 + wv * 32 + c2 * 16 + lrow];
      #pragma unroll
      for (int c2 = 0; c2 < 2; ++c2)
        #pragma unroll
        for (int mt = 0; mt < 4; ++mt)
          acc4[c2][mt] = MFMA16(aw[c2], by[mt], acc4[c2][mt]);
    }
    __builtin_amdgcn_s_setprio(0);
    // stores: ch = wv*32 + c2*16 + lhi*4 + i, m = mt*16 + lrow -> 64B-coalesced
    const long obase = (long)(bidx * 256 + wv * 32 + lhi * 4) * 16384 + h * 128 + w0 + lrow;
    #pragma unroll
    for (int c2 = 0; c2 < 2; ++c2)
      #pragma unroll
      for (int i = 0; i < 4; ++i)
        #pragma unroll
        for (int mt = 0; mt < 4; ++mt)
          __builtin_nontemporal_store(acc4[c2][mt][i],
              out + obase + (long)(c2 * 16 + i) * 16384 + mt * 16);
  }
}

extern "C" void kernel_launch(void* const* d_in, const int* in_sizes, int n_in,
                              void* d_out, int out_size, void* d_ws, size_t ws_size,
                              hipStream_t stream) {
  const float* x       = (const float*)d_in[0];
  const float* W_in    = (const float*)d_in[1];
  const float* conv_w  = (const float*)d_in[2];
  const float* conv_b  = (const float*)d_in[3];
  const float* W_xproj = (const float*)d_in[4];
  const float* W_dt    = (const float*)d_in[5];
  const float* b_dt    = (const float*)d_in[6];
  // d_in[7] = A_log: unused by the reference's L=1 path
  const float* Dvec    = (const float*)d_in[8];
  const float* W_out   = (const float*)d_in[9];
  float* out = (float*)d_out;
  char* ws = (char*)d_ws;

  // pack weights to f16 fragment layout (once per launch, ~870 KB)
  pack_win_kernel<<<dim3(1024), dim3(256), 0, stream>>>(W_in, conv_w, (unsigned short*)(ws + WPIN_OFF));
  pack_w_kernel<<<dim3(512),  dim3(256), 0, stream>>>(W_out,   (unsigned short*)(ws + WPOUT_OFF), 512, 256, 64);
  pack_w_kernel<<<dim3(96),   dim3(256), 0, stream>>>(W_xproj, (unsigned short*)(ws + WPXP_OFF), 512, 48, 64);
  pack_w_kernel<<<dim3(64),   dim3(256), 0, stream>>>(W_dt,    (unsigned short*)(ws + WPDT_OFF), 16, 512, 4);

  // 2048 workgroups x 512 threads; each handles 64 rows (one half w-line)
  mamba_fused_kernel<<<dim3(2048), dim3(512), 0, stream>>>(
      x, conv_b, b_dt, Dvec, out, (const char*)ws);
}